// Round 3
// baseline (62.304 us; speedup 1.0000x reference)
//
#include <hip/hip_runtime.h>

#define EPSF 1e-7f
#define SCALEF (1.0f / 7.0f)

__device__ __forceinline__ float pair_iou(const float* b1, const float* b2) {
    float b1x1 = b1[0] - b1[2] * 0.5f, b1x2 = b1[0] + b1[2] * 0.5f;
    float b1y1 = b1[1] - b1[3] * 0.5f, b1y2 = b1[1] + b1[3] * 0.5f;
    float b2x1 = b2[0] - b2[2] * 0.5f, b2x2 = b2[0] + b2[2] * 0.5f;
    float b2y1 = b2[1] - b2[3] * 0.5f, b2y2 = b2[1] + b2[3] * 0.5f;
    float iw = fmaxf(fminf(b1x2, b2x2) - fmaxf(b1x1, b2x1), 0.0f);
    float ih = fmaxf(fminf(b1y2, b2y2) - fmaxf(b1y1, b2y1), 0.0f);
    float inter = iw * ih + EPSF;
    float w1 = b1x2 - b1x1, h1 = b1y2 - b1y1 + EPSF;
    float w2 = b2x2 - b2x1, h2 = b2y2 - b2y1 + EPSF;
    float uni = w1 * h1 + w2 * h2 - inter + EPSF;
    return inter / uni;
}

// Block = 256 threads, handles 256 cells in 2 chunks of 128.
// Per chunk: coalesced float4 staging of 128 cells x 30 floats x 2 arrays
// into linear LDS (30720 B -> 5 blocks/CU), then wave-uniform split:
// waves 0-1 compute box/conf terms (floats 0..9), waves 2-3 class (10..29).
// Block partial is folded into out[0] via one atomicAdd per block
// (out zeroed by hipMemsetAsync each call; fp-ordering noise ~1e-4 << tol).
__global__ __launch_bounds__(256) void yolo_loss(
        const float* __restrict__ pre, const float* __restrict__ targ,
        float invB, float* __restrict__ out) {
    __shared__ float4 s4[1920];                      // [0,960) = pre, [960,1920) = targ
    float* sp = reinterpret_cast<float*>(s4);
    float* st = reinterpret_cast<float*>(s4 + 960);
    const int tid = threadIdx.x;
    float acc = 0.0f;

#pragma unroll
    for (int chunk = 0; chunk < 2; ++chunk) {
        const size_t base = ((size_t)blockIdx.x * 256 + chunk * 128) * 30;
        const float4* gp = reinterpret_cast<const float4*>(pre + base);
        const float4* gt = reinterpret_cast<const float4*>(targ + base);
        float4* sp4 = s4;
        float4* st4 = s4 + 960;
#pragma unroll
        for (int k = 0; k < 3; ++k) {                // 960 float4 per array, 256 threads
            int idx = tid + 256 * k;
            sp4[idx] = gp[idx];
            st4[idx] = gt[idx];
        }
        {
            int idx = tid + 768;
            if (idx < 960) { sp4[idx] = gp[idx]; st4[idx] = gt[idx]; }
        }
        __syncthreads();

        const int half = tid >> 7;                   // wave-uniform: waves 0-1 box, 2-3 class
        const int c = tid & 127;
        const float* cp = sp + c * 30;
        const float* ct = st + c * 30;
        float loss = 0.0f;
        if (half == 0) {
            float p[10], t[10];
            const float2* cp2 = reinterpret_cast<const float2*>(cp);
            const float2* ct2 = reinterpret_cast<const float2*>(ct);
#pragma unroll
            for (int i = 0; i < 5; ++i) {
                float2 a = cp2[i]; p[2 * i] = a.x; p[2 * i + 1] = a.y;
                float2 b = ct2[i]; t[2 * i] = b.x; t[2 * i + 1] = b.y;
            }
            bool cell_obj   = t[4] > 0.0f;
            bool cell_noobj = t[4] == 0.0f;
            float iou0 = pair_iou(p + 0, t + 0);
            float iou1 = pair_iou(p + 5, t + 5);
            int resp    = (iou1 > iou0) ? 1 : 0;     // jnp.argmax first-index semantics
            int nonresp = (iou1 < iou0) ? 1 : 0;
            float xnr = nonresp ? t[5] : t[0];
            float ynr = nonresp ? t[6] : t[1];
            float fx = (xnr - (ceilf(xnr / SCALEF) - 1.0f) * SCALEF) / SCALEF;
            float fy = (ynr - (ceilf(ynr / SCALEF) - 1.0f) * SCALEF) / SCALEF;
            float lxy = 0.0f, lwh = 0.0f, lconf = 0.0f, lnoconf = 0.0f;
#pragma unroll
            for (int i = 0; i < 2; ++i) {
                const float* pb = p + i * 5;
                const float* tb = t + i * 5;
                bool is_resp    = (i == resp);
                bool is_nonresp = (i == nonresp);
                float new_conf = is_nonresp ? 0.0f : tb[4];
                if (cell_obj) {
                    if (is_resp) {
                        float dx = pb[0] - fx, dy = pb[1] - fy;
                        lxy += dx * dx + dy * dy;
                        float dw = sqrtf(pb[2] + EPSF) - sqrtf(tb[2] + EPSF);
                        float dh = sqrtf(pb[3] + EPSF) - sqrtf(tb[3] + EPSF);
                        lwh += dw * dw + dh * dh;
                        float dc = pb[4] - new_conf;
                        lconf += dc * dc;
                    } else {
                        float dc = pb[4] - new_conf;
                        lnoconf += dc * dc;
                    }
                }
                if (cell_noobj) {
                    float dc = pb[4] - tb[4];
                    lnoconf += dc * dc;
                }
            }
            loss = 5.0f * (lxy + lwh) + lconf + 0.5f * lnoconf;
        } else {
            float tobj = ct[4];
            if (tobj > 0.0f) {
                float s = 0.0f;
                const float2* cp2 = reinterpret_cast<const float2*>(cp + 10);
                const float2* ct2 = reinterpret_cast<const float2*>(ct + 10);
#pragma unroll
                for (int i = 0; i < 10; ++i) {
                    float2 a = cp2[i], b = ct2[i];
                    float d0 = a.x - b.x, d1 = a.y - b.y;
                    s += d0 * d0 + d1 * d1;
                }
                loss = s;
            }
        }
        acc += loss;
        __syncthreads();                             // protect LDS reuse by next chunk
    }

    // wave64 shuffle reduce, then cross-wave via LDS, then one atomic per block
#pragma unroll
    for (int off = 32; off > 0; off >>= 1) acc += __shfl_down(acc, off, 64);
    __shared__ float ssum[4];
    int lane = tid & 63, wid = tid >> 6;
    if (lane == 0) ssum[wid] = acc;
    __syncthreads();
    if (tid == 0) {
        float block_sum = ssum[0] + ssum[1] + ssum[2] + ssum[3];
        atomicAdd(out, block_sum * invB);
    }
}

extern "C" void kernel_launch(void* const* d_in, const int* in_sizes, int n_in,
                              void* d_out, int out_size, void* d_ws, size_t ws_size,
                              hipStream_t stream) {
    const float* pre  = (const float*)d_in[0];
    const float* targ = (const float*)d_in[1];
    float* out = (float*)d_out;

    int B = in_sizes[0] / 1470;            // 16384
    int n_cells = B * 49;                  // 802816 = 3136 * 256 exactly
    int nblocks = n_cells / 256;           // 3136

    hipMemsetAsync(out, 0, sizeof(float), stream);   // atomic accumulator reset (capture-safe)
    yolo_loss<<<nblocks, 256, 0, stream>>>(pre, targ, 1.0f / (float)B, out);
}

// Round 4
// 38.084 us; speedup vs baseline: 1.6360x; 1.6360x over previous
//
#include <hip/hip_runtime.h>

#define EPSF 1e-7f
#define SCALEF (1.0f / 7.0f)

__device__ __forceinline__ float pair_iou(const float* b1, const float* b2) {
    float b1x1 = b1[0] - b1[2] * 0.5f, b1x2 = b1[0] + b1[2] * 0.5f;
    float b1y1 = b1[1] - b1[3] * 0.5f, b1y2 = b1[1] + b1[3] * 0.5f;
    float b2x1 = b2[0] - b2[2] * 0.5f, b2x2 = b2[0] + b2[2] * 0.5f;
    float b2y1 = b2[1] - b2[3] * 0.5f, b2y2 = b2[1] + b2[3] * 0.5f;
    float iw = fmaxf(fminf(b1x2, b2x2) - fmaxf(b1x1, b2x1), 0.0f);
    float ih = fmaxf(fminf(b1y2, b2y2) - fmaxf(b1y1, b2y1), 0.0f);
    float inter = iw * ih + EPSF;
    float w1 = b1x2 - b1x1, h1 = b1y2 - b1y1 + EPSF;
    float w2 = b2x2 - b2x1, h2 = b2y2 - b2y1 + EPSF;
    float uni = w1 * h1 + w2 * h2 - inter + EPSF;
    return inter / uni;
}

// Direct global->LDS DMA (16B/lane). LDS dest must be wave-uniform base +
// lane*16 (linear), which our staging layout satisfies exactly.
__device__ __forceinline__ void gload_lds16(const float4* g, float4* l) {
    __builtin_amdgcn_global_load_lds(
        (const __attribute__((address_space(1))) unsigned int*)g,
        (__attribute__((address_space(3))) unsigned int*)l,
        16, 0, 0);
}

// Block = 256 threads, 256 cells in 2 chunks of 128.
// Per chunk: global_load_lds staging of 128 cells x 30 floats x 2 arrays
// (no VGPR round-trip, no ds_write), then wave-uniform split:
// waves 0-1 box/conf terms (floats 0..9), waves 2-3 class (10..29).
// Deterministic block partials -> d_ws; tiny second kernel reduces.
// (Round-3 lesson: 3136 atomicAdds to one line serialize ~25us — never again.)
__global__ __launch_bounds__(256) void yolo_loss_partial(
        const float* __restrict__ pre, const float* __restrict__ targ,
        float* __restrict__ partial) {
    __shared__ float4 s4[1920];                      // [0,960) = pre, [960,1920) = targ
    float* sp = reinterpret_cast<float*>(s4);
    float* st = reinterpret_cast<float*>(s4 + 960);
    const int tid = threadIdx.x;
    const int wid = tid >> 6;
    float acc = 0.0f;

#pragma unroll
    for (int chunk = 0; chunk < 2; ++chunk) {
        const size_t base = ((size_t)blockIdx.x * 256 + chunk * 128) * 30;
        const float4* gp = reinterpret_cast<const float4*>(pre + base);
        const float4* gt = reinterpret_cast<const float4*>(targ + base);
        float4* sp4 = s4;
        float4* st4 = s4 + 960;
#pragma unroll
        for (int k = 0; k < 3; ++k) {                // 3*256 = 768 of 960 float4 per array
            int idx = tid + 256 * k;
            gload_lds16(gp + idx, sp4 + (wid * 64 + 256 * k));   // wave-uniform LDS base
            gload_lds16(gt + idx, st4 + (wid * 64 + 256 * k));
        }
        if (tid < 192) {                              // tail 768..959: waves 0-2 exactly (uniform)
            int idx = tid + 768;
            gload_lds16(gp + idx, sp4 + (wid * 64 + 768));
            gload_lds16(gt + idx, st4 + (wid * 64 + 768));
        }
        __syncthreads();                              // drains vmcnt -> LDS valid

        const int half = tid >> 7;                    // wave-uniform: waves 0-1 box, 2-3 class
        const int c = tid & 127;
        const float* cp = sp + c * 30;
        const float* ct = st + c * 30;
        float loss = 0.0f;
        if (half == 0) {
            float p[10], t[10];
            const float2* cp2 = reinterpret_cast<const float2*>(cp);
            const float2* ct2 = reinterpret_cast<const float2*>(ct);
#pragma unroll
            for (int i = 0; i < 5; ++i) {
                float2 a = cp2[i]; p[2 * i] = a.x; p[2 * i + 1] = a.y;
                float2 b = ct2[i]; t[2 * i] = b.x; t[2 * i + 1] = b.y;
            }
            bool cell_obj   = t[4] > 0.0f;
            bool cell_noobj = t[4] == 0.0f;
            float iou0 = pair_iou(p + 0, t + 0);
            float iou1 = pair_iou(p + 5, t + 5);
            int resp    = (iou1 > iou0) ? 1 : 0;      // jnp.argmax first-index semantics
            int nonresp = (iou1 < iou0) ? 1 : 0;
            float xnr = nonresp ? t[5] : t[0];
            float ynr = nonresp ? t[6] : t[1];
            float fx = (xnr - (ceilf(xnr / SCALEF) - 1.0f) * SCALEF) / SCALEF;
            float fy = (ynr - (ceilf(ynr / SCALEF) - 1.0f) * SCALEF) / SCALEF;
            float lxy = 0.0f, lwh = 0.0f, lconf = 0.0f, lnoconf = 0.0f;
#pragma unroll
            for (int i = 0; i < 2; ++i) {
                const float* pb = p + i * 5;
                const float* tb = t + i * 5;
                bool is_resp    = (i == resp);
                bool is_nonresp = (i == nonresp);
                float new_conf = is_nonresp ? 0.0f : tb[4];
                if (cell_obj) {
                    if (is_resp) {
                        float dx = pb[0] - fx, dy = pb[1] - fy;
                        lxy += dx * dx + dy * dy;
                        float dw = sqrtf(pb[2] + EPSF) - sqrtf(tb[2] + EPSF);
                        float dh = sqrtf(pb[3] + EPSF) - sqrtf(tb[3] + EPSF);
                        lwh += dw * dw + dh * dh;
                        float dc = pb[4] - new_conf;
                        lconf += dc * dc;
                    } else {
                        float dc = pb[4] - new_conf;
                        lnoconf += dc * dc;
                    }
                }
                if (cell_noobj) {
                    float dc = pb[4] - tb[4];
                    lnoconf += dc * dc;
                }
            }
            loss = 5.0f * (lxy + lwh) + lconf + 0.5f * lnoconf;
        } else {
            float tobj = ct[4];
            if (tobj > 0.0f) {
                float s = 0.0f;
                const float2* cp2 = reinterpret_cast<const float2*>(cp + 10);
                const float2* ct2 = reinterpret_cast<const float2*>(ct + 10);
#pragma unroll
                for (int i = 0; i < 10; ++i) {
                    float2 a = cp2[i], b = ct2[i];
                    float d0 = a.x - b.x, d1 = a.y - b.y;
                    s += d0 * d0 + d1 * d1;
                }
                loss = s;
            }
        }
        acc += loss;
        __syncthreads();                              // protect LDS reuse by next chunk
    }

    // wave64 shuffle reduce, then cross-wave via LDS
#pragma unroll
    for (int off = 32; off > 0; off >>= 1) acc += __shfl_down(acc, off, 64);
    __shared__ float ssum[4];
    int lane = tid & 63;
    if (lane == 0) ssum[wid] = acc;
    __syncthreads();
    if (tid == 0) partial[blockIdx.x] = ssum[0] + ssum[1] + ssum[2] + ssum[3];
}

__global__ __launch_bounds__(256) void yolo_loss_final(
        const float* __restrict__ partial, int n, float invB, float* __restrict__ out) {
    float v = 0.0f;
    for (int i = threadIdx.x; i < n; i += 256) v += partial[i];
#pragma unroll
    for (int off = 32; off > 0; off >>= 1) v += __shfl_down(v, off, 64);
    __shared__ float ssum[4];
    int lane = threadIdx.x & 63, wid = threadIdx.x >> 6;
    if (lane == 0) ssum[wid] = v;
    __syncthreads();
    if (threadIdx.x == 0) out[0] = (ssum[0] + ssum[1] + ssum[2] + ssum[3]) * invB;
}

extern "C" void kernel_launch(void* const* d_in, const int* in_sizes, int n_in,
                              void* d_out, int out_size, void* d_ws, size_t ws_size,
                              hipStream_t stream) {
    const float* pre  = (const float*)d_in[0];
    const float* targ = (const float*)d_in[1];
    float* out = (float*)d_out;
    float* partial = (float*)d_ws;

    int B = in_sizes[0] / 1470;            // 16384
    int n_cells = B * 49;                  // 802816 = 3136 * 256 exactly
    int nblocks = n_cells / 256;           // 3136

    yolo_loss_partial<<<nblocks, 256, 0, stream>>>(pre, targ, partial);
    yolo_loss_final<<<1, 256, 0, stream>>>(partial, nblocks, 1.0f / (float)B, out);
}